// Round 10
// baseline (824.571 us; speedup 1.0000x reference)
//
#include <hip/hip_runtime.h>
#include <hip/hip_bf16.h>

// GAT (2-layer, 8-head) on gfx950 — single persistent kernel, 1024 blocks
// (4/CU x 256 CU co-resident), software grid barriers between phases.
// d_out = [h2: 2048*512 | att1: 8*2048*2048 | att2: 8*2048*2048] float32.

typedef __attribute__((ext_vector_type(8))) short bf16x8;
typedef __attribute__((ext_vector_type(4))) float f32x4;

__device__ __forceinline__ float bf2f(unsigned short u) {
    return __uint_as_float(((unsigned int)u) << 16);
}
__device__ __forceinline__ unsigned short f2bf(float f) {
    __hip_bfloat16 h = __float2bfloat16(f);
    return __builtin_bit_cast(unsigned short, h);
}
__device__ __forceinline__ float elu1(float x) { return x > 0.f ? x : expm1f(x); }

// device-scope grid barrier (monotone counter; bounded spin -> fails visibly,
// never hangs, if co-residency assumption is ever violated)
__device__ __forceinline__ void gridbar(unsigned* cnt, unsigned target) {
    __syncthreads();
    if (threadIdx.x == 0) {
        __threadfence();
        atomicAdd(cnt, 1u);
        long spin = 0;
        while (atomicAdd(cnt, 0u) < target && spin < (1L << 22)) {
            __builtin_amdgcn_s_sleep(2);
            ++spin;
        }
        __threadfence();
    }
    __syncthreads();
}

__global__ void init_cnt_kernel(unsigned* cnt) { *cnt = 0u; }

// ---------------------------------------------------------------------------
// Phase bodies (shared-LDS pool reused across phases; barrier-separated).
// Pool layout:
//   gemm : accredG[4][64][20] f32                      (20480 B)
//   fused: lbits[16*65] u32 (4160) | ls2[2048] f32 (8192) | lmax/lsum (512)
//          | pstage[4][16][9] f32x4 UNION accredF[3][64][20] f32 (15360)
//   total 28224 B -> 4 blocks/CU.
// ---------------------------------------------------------------------------

__device__ __forceinline__ void gemm_phase(
    char* pool, int bx, int tid,
    const float* __restrict__ A,
    const unsigned short* __restrict__ BpHi, const unsigned short* __restrict__ BpLo,
    const float* __restrict__ avec,
    unsigned short* __restrict__ Whp, float* __restrict__ s1, float* __restrict__ s2) {
    float (*accredG)[64][20] = reinterpret_cast<float(*)[64][20]>(pool);
    const int h    = bx >> 7;
    const int mt   = bx & 127;
    const int wave = tid >> 6;     // 4-way K split (128 each)
    const int lane = tid & 63;
    const int quad = lane >> 4;
    const int m16  = lane & 15;
    const int rowbase = mt * 16;

    const float* Arow = A + (long)(rowbase + m16) * 512 + wave * 128 + quad * 8;
    const long boff = ((long)(h * 16 + wave * 4) * 64 + m16) * 32 + quad * 8;
    const unsigned short* BH = BpHi + boff;
    const unsigned short* BL = BpLo + boff;

    f32x4 acc[4];
#pragma unroll
    for (int t = 0; t < 4; ++t)
#pragma unroll
        for (int r = 0; r < 4; ++r) acc[t][r] = 0.f;

#pragma unroll
    for (int kb = 0; kb < 4; ++kb) {
        const float* ap = Arow + kb * 32;
        bf16x8 ahi, alo;
#pragma unroll
        for (int j = 0; j < 8; ++j) {
            float v = ap[j];
            unsigned short hv = f2bf(v);
            ahi[j] = (short)hv;
            alo[j] = (short)f2bf(v - bf2f(hv));
        }
        const unsigned short* bh0 = BH + (long)kb * 2048;
        const unsigned short* bl0 = BL + (long)kb * 2048;
#pragma unroll
        for (int t = 0; t < 4; ++t) {
            bf16x8 bh = *reinterpret_cast<const bf16x8*>(bh0 + t * 512);
            bf16x8 bl = *reinterpret_cast<const bf16x8*>(bl0 + t * 512);
            acc[t] = __builtin_amdgcn_mfma_f32_16x16x32_bf16(alo, bh, acc[t], 0, 0, 0);
            acc[t] = __builtin_amdgcn_mfma_f32_16x16x32_bf16(ahi, bl, acc[t], 0, 0, 0);
            acc[t] = __builtin_amdgcn_mfma_f32_16x16x32_bf16(ahi, bh, acc[t], 0, 0, 0);
        }
    }

#pragma unroll
    for (int t = 0; t < 4; ++t)
        *reinterpret_cast<f32x4*>(&accredG[wave][t * 16 + m16][quad * 4]) = acc[t];
    __syncthreads();
    if (wave != 0) return;

#pragma unroll
    for (int w = 1; w < 4; ++w)
#pragma unroll
        for (int t = 0; t < 4; ++t) {
            f32x4 o = *reinterpret_cast<const f32x4*>(&accredG[w][t * 16 + m16][quad * 4]);
#pragma unroll
            for (int r = 0; r < 4; ++r) acc[t][r] += o[r];
        }

    // ---- s1/s2 epilogue ----
    float aS[4], aD[4];
#pragma unroll
    for (int t = 0; t < 4; ++t) {
        aS[t] = avec[(h << 7) + t * 16 + m16];
        aD[t] = avec[(h << 7) + 64 + t * 16 + m16];
    }
#pragma unroll
    for (int r = 0; r < 4; ++r) {
        float t1 = 0.f, t2 = 0.f;
#pragma unroll
        for (int t = 0; t < 4; ++t) {
            float v = acc[t][r];
            t1 = fmaf(v, aS[t], t1);
            t2 = fmaf(v, aD[t], t2);
        }
#pragma unroll
        for (int off = 1; off < 16; off <<= 1) {
            t1 += __shfl_xor(t1, off);
            t2 += __shfl_xor(t2, off);
        }
        if (m16 == 0) {
            int row = rowbase + quad * 4 + r;
            s1[(h << 11) + row] = t1;
            s2[(h << 11) + row] = t2;
        }
    }

    // ---- store Wh bf16 fragment-packed ----
#pragma unroll
    for (int t = 0; t < 4; ++t) {
        const int col = t * 16 + m16;
#pragma unroll
        for (int r = 0; r < 4; ++r) {
            const int row = rowbase + quad * 4 + r;
            long idx = (((long)(h * 64 + (row >> 5)) * 64 + col) << 5) + (row & 31);
            Whp[idx] = f2bf(acc[t][r]);
        }
    }
}

__device__ __forceinline__ void fused_phase(
    char* pool, int bx, int tid,
    const float* __restrict__ s1g, const float* __restrict__ s2g,
    const unsigned int* __restrict__ gbits,
    const unsigned short* __restrict__ Whp,
    float* __restrict__ att, float* __restrict__ hout) {
    unsigned int* lbits = reinterpret_cast<unsigned int*>(pool);            // 16*65
    float* ls2          = reinterpret_cast<float*>(pool + 4160);            // 2048
    float (*lmax)[16]   = reinterpret_cast<float(*)[16]>(pool + 12352);
    float (*lsum)[16]   = reinterpret_cast<float(*)[16]>(pool + 12608);
    f32x4 (*pstage)[16][9]  = reinterpret_cast<f32x4(*)[16][9]>(pool + 12864);
    float (*accredF)[64][20] = reinterpret_cast<float(*)[64][20]>(pool + 12864);

    const int h    = bx >> 7;
    const int row0 = (bx & 127) << 4;
    const int wq   = tid >> 6;
    const int lane = tid & 63;
    const int quad = lane >> 4;
    const int m16  = lane & 15;

#pragma unroll
    for (int i = 0; i < 4; ++i) {
        int idx = i * 256 + tid;
        lbits[(idx >> 6) * 65 + (idx & 63)] = gbits[((row0 + (idx >> 6)) << 6) + (idx & 63)];
    }
    const float4* s2v4 = reinterpret_cast<const float4*>(s2g + (h << 11));
#pragma unroll
    for (int i = 0; i < 2; ++i) {
        int idx = i * 256 + tid;
        reinterpret_cast<float4*>(ls2)[idx] = s2v4[idx];
    }
    __syncthreads();

    const float s1i = s1g[(h << 11) + row0 + m16];

    // ---- P12: fused online masked max+sum over this wave's 16 words ----
    float mx = -INFINITY;
    float lp = 0.f;
    for (int i = 0; i < 16; ++i) {
        const int jt = wq * 16 + i;
        unsigned int word = lbits[m16 * 65 + jt] >> (quad * 8);
        float4 sa = *reinterpret_cast<const float4*>(ls2 + jt * 32 + quad * 8);
        float4 sb = *reinterpret_cast<const float4*>(ls2 + jt * 32 + quad * 8 + 4);
        float sv[8] = {sa.x, sa.y, sa.z, sa.w, sb.x, sb.y, sb.z, sb.w};
        float ev[8];
        float bm = -INFINITY;
#pragma unroll
        for (int u = 0; u < 8; ++u) {
            float e = s1i + sv[u];
            e = fmaxf(e, 0.2f * e);
            ev[u] = e;
            bm = fmaxf(bm, ((word >> u) & 1u) ? e : -INFINITY);
        }
        float nm = fmaxf(mx, bm);
        float sc = (mx == nm) ? 1.f : __expf(mx - nm);
        lp *= sc;
        mx = nm;
#pragma unroll
        for (int u = 0; u < 8; ++u)
            lp += ((word >> u) & 1u) ? __expf(ev[u] - mx) : 0.f;
    }
#pragma unroll
    for (int off = 16; off < 64; off <<= 1) {
        float omx = __shfl_xor(mx, off);
        float olp = __shfl_xor(lp, off);
        float nm = fmaxf(mx, omx);
        float sa = (mx == nm) ? 1.f : __expf(mx - nm);
        float sb = (omx == nm) ? 1.f : __expf(omx - nm);
        lp = fmaf(lp, sa, olp * sb);
        mx = nm;
    }
    if (lane < 16) {
        lmax[wq][m16] = mx;
        lsum[wq][m16] = lp;
    }
    __syncthreads();
    float m = fmaxf(fmaxf(lmax[0][m16], lmax[1][m16]),
                    fmaxf(lmax[2][m16], lmax[3][m16]));
    float l = 0.f;
#pragma unroll
    for (int w = 0; w < 4; ++w) {
        float wm = lmax[w][m16];
        float ws = (wm == m) ? 1.f : __expf(wm - m);
        l = fmaf(lsum[w][m16], ws, l);
    }
    const bool am = (m == -INFINITY);
    const float invl = am ? 0.f : 1.f / l;
    const float fallb = 1.f / 2048.f;

    // ---- P3: att write (LDS-staged packed NT) + PV MFMA ----
    f32x4 acc[4];
#pragma unroll
    for (int t = 0; t < 4; ++t)
#pragma unroll
        for (int r = 0; r < 4; ++r) acc[t][r] = 0.f;

    const unsigned short* BW = Whp + ((long)(h << 12) + m16) * 32 + quad * 8;
    float* attbase = att + (long)h * 4194304 + (long)row0 * 2048;
    const int fr = lane >> 3;
    const int fc = lane & 7;

    for (int i = 0; i < 16; ++i) {
        const int jt = wq * 16 + i;
        unsigned int word = lbits[m16 * 65 + jt];
        float4 sa = *reinterpret_cast<const float4*>(ls2 + jt * 32 + quad * 8);
        float4 sb = *reinterpret_cast<const float4*>(ls2 + jt * 32 + quad * 8 + 4);
        float sv[8] = {sa.x, sa.y, sa.z, sa.w, sb.x, sb.y, sb.z, sb.w};
        float p[8];
        bf16x8 af;
#pragma unroll
        for (int u = 0; u < 8; ++u) {
            float e = s1i + sv[u];
            e = fmaxf(e, 0.2f * e);
            float pv = ((word >> (quad * 8 + u)) & 1u) ? __expf(e - m) * invl : 0.f;
            p[u] = am ? fallb : pv;
            af[u] = (short)f2bf(p[u]);
        }
        f32x4 plo, phi;
        plo[0] = p[0]; plo[1] = p[1]; plo[2] = p[2]; plo[3] = p[3];
        phi[0] = p[4]; phi[1] = p[5]; phi[2] = p[6]; phi[3] = p[7];
        pstage[wq][m16][quad * 2]     = plo;
        pstage[wq][m16][quad * 2 + 1] = phi;

        const unsigned short* b0 = BW + (long)jt * 2048;
#pragma unroll
        for (int t = 0; t < 4; ++t) {
            bf16x8 bf = *reinterpret_cast<const bf16x8*>(b0 + t * 512);
            acc[t] = __builtin_amdgcn_mfma_f32_16x16x32_bf16(af, bf, acc[t], 0, 0, 0);
        }

#pragma unroll
        for (int half = 0; half < 2; ++half) {
            const int r = half * 8 + fr;
            f32x4 v = pstage[wq][r][fc];
            __builtin_nontemporal_store(
                v, reinterpret_cast<f32x4*>(attbase + (long)r * 2048 + jt * 32 + fc * 4));
        }
    }

    // ---- reduce partial PV across waves (pool reuse barrier first) ----
    __syncthreads();
    if (wq > 0) {
#pragma unroll
        for (int t = 0; t < 4; ++t)
            *reinterpret_cast<f32x4*>(&accredF[wq - 1][t * 16 + m16][quad * 4]) = acc[t];
    }
    __syncthreads();
    if (wq == 0) {
#pragma unroll
        for (int t = 0; t < 4; ++t) {
            const int col = t * 16 + m16;
#pragma unroll
            for (int w = 0; w < 3; ++w) {
                f32x4 o = *reinterpret_cast<const f32x4*>(&accredF[w][col][quad * 4]);
#pragma unroll
                for (int r = 0; r < 4; ++r) acc[t][r] += o[r];
            }
#pragma unroll
            for (int r = 0; r < 4; ++r) {
                const int row = row0 + quad * 4 + r;
                hout[(row << 9) + (h << 6) + col] = elu1(elu1(acc[t][r]));
            }
        }
    }
}

// ---------------------------------------------------------------------------
__global__ __launch_bounds__(256, 4) void gat_persistent(
    const float* __restrict__ x, const int* __restrict__ adj,
    const float* __restrict__ W1, const float* __restrict__ a1,
    const float* __restrict__ W2, const float* __restrict__ a2,
    float* __restrict__ out, float* __restrict__ att1, float* __restrict__ att2,
    unsigned short* __restrict__ Wp1Hi, unsigned short* __restrict__ Wp1Lo,
    unsigned short* __restrict__ Wp2Hi, unsigned short* __restrict__ Wp2Lo,
    unsigned short* __restrict__ Whp, float* __restrict__ s1, float* __restrict__ s2,
    unsigned long long* __restrict__ gbits, float* __restrict__ x2,
    unsigned* __restrict__ cnt) {
    __shared__ __align__(16) char pool[28224];
    const int bx  = blockIdx.x;   // 1024
    const int tid = threadIdx.x;

    // ---- phase 0: prep (adjbits grid-strided + W1/W2 reorder) ----
#pragma unroll
    for (int i = 0; i < 16; ++i) {
        int g = bx * 4096 + i * 256 + tid;
        unsigned long long mb = __ballot(adj[g] > 0);
        if ((tid & 63) == 0) gbits[g >> 6] = mb;
    }
    {
        int idx = bx * 256 + tid;   // 1024*256 = 262144 exactly (one elem/thread)
        int o = idx & 63;
        int k = (idx >> 6) & 511;
        int h = idx >> 15;
        long widx = (((h * 16) + (k >> 5)) * 64 + o) * 32 + (k & 31);
        float v1 = W1[idx];
        unsigned short h1 = f2bf(v1);
        Wp1Hi[widx] = h1;
        Wp1Lo[widx] = f2bf(v1 - bf2f(h1));
        float v2 = W2[idx];
        unsigned short h2 = f2bf(v2);
        Wp2Hi[widx] = h2;
        Wp2Lo[widx] = f2bf(v2 - bf2f(h2));
    }
    gridbar(cnt, 1024);

    const unsigned int* gbits32 = (const unsigned int*)gbits;

    // ---- layer 1 ----
    gemm_phase(pool, bx, tid, x, Wp1Hi, Wp1Lo, a1, Whp, s1, s2);
    gridbar(cnt, 2048);
    fused_phase(pool, bx, tid, s1, s2, gbits32, Whp, att1, x2);
    gridbar(cnt, 3072);

    // ---- layer 2 ----
    gemm_phase(pool, bx, tid, x2, Wp2Hi, Wp2Lo, a2, Whp, s1, s2);
    gridbar(cnt, 4096);
    fused_phase(pool, bx, tid, s1, s2, gbits32, Whp, att2, out);
}

// ---------------------------------------------------------------------------
extern "C" void kernel_launch(void* const* d_in, const int* in_sizes, int n_in,
                              void* d_out, int out_size, void* d_ws, size_t ws_size,
                              hipStream_t stream) {
    const float* x  = (const float*)d_in[0];   // [2048][512]
    const int* adj  = (const int*)d_in[1];     // [2048][2048]
    const float* W1 = (const float*)d_in[2];   // [8][512][64]
    const float* a1 = (const float*)d_in[3];   // [8][128]
    const float* W2 = (const float*)d_in[4];
    const float* a2 = (const float*)d_in[5];

    float* out  = (float*)d_out;       // h2 [2048][512]
    float* att1 = out + 1048576;       // [8][2048][2048]
    float* att2 = att1 + 33554432;

    char* w = (char*)d_ws;
    unsigned short* Wp1Hi = (unsigned short*)(w);             // 512 KB
    unsigned short* Wp1Lo = (unsigned short*)(w + 524288);    // 512 KB
    unsigned short* Wp2Hi = (unsigned short*)(w + 1048576);   // 512 KB
    unsigned short* Wp2Lo = (unsigned short*)(w + 1572864);   // 512 KB
    unsigned short* Whp   = (unsigned short*)(w + 2097152);   // 2 MB
    float* s1             = (float*)(w + 4194304);            // 64 KB
    float* s2             = (float*)(w + 4259840);            // 64 KB
    unsigned long long* gbits = (unsigned long long*)(w + 4325376);  // 512 KB
    float* x2             = (float*)(w + 4849664);            // 4 MB
    unsigned* cnt         = (unsigned*)(w + 9043968);         // 4 B

    init_cnt_kernel<<<1, 1, 0, stream>>>(cnt);
    gat_persistent<<<1024, 256, 0, stream>>>(
        x, adj, W1, a1, W2, a2, out, att1, att2,
        Wp1Hi, Wp1Lo, Wp2Hi, Wp2Lo, Whp, s1, s2, gbits, x2, cnt);
}

// Round 11
// 371.187 us; speedup vs baseline: 2.2214x; 2.2214x over previous
//
#include <hip/hip_runtime.h>
#include <hip/hip_bf16.h>

// GAT (2-layer, 8-head) on gfx950. Inputs f32 (adj int32), outputs f32.
// d_out = [h2: 2048*512 | att1: 8*2048*2048 | att2: 8*2048*2048] float32.

typedef __attribute__((ext_vector_type(8))) short bf16x8;
typedef __attribute__((ext_vector_type(4))) float f32x4;

__device__ __forceinline__ float bf2f(unsigned short u) {
    return __uint_as_float(((unsigned int)u) << 16);
}
__device__ __forceinline__ unsigned short f2bf(float f) {
    __hip_bfloat16 h = __float2bfloat16(f);
    return __builtin_bit_cast(unsigned short, h);
}
__device__ __forceinline__ float elu1(float x) { return x > 0.f ? x : expm1f(x); }

// ---------------------------------------------------------------------------
// adj [2048][2048] int32 -> bitmask [2048][64] u32 (u64 stores via ballot).
// ---------------------------------------------------------------------------
__global__ __launch_bounds__(256) void adjbits_kernel(
    const int* __restrict__ adj, unsigned long long* __restrict__ gbits) {
    int g = blockIdx.x * 256 + threadIdx.x;  // 4194304 threads
    unsigned long long m = __ballot(adj[g] > 0);
    if ((threadIdx.x & 63) == 0) gbits[g >> 6] = m;
}

// ---------------------------------------------------------------------------
// Reorder W [8][512][64] (f32) into split-bf16 MFMA B-fragment packing:
// Wp{Hi,Lo}[h][kb][col][k&31], k = kb*32 + (quad*8+j).
// ---------------------------------------------------------------------------
__global__ __launch_bounds__(256) void reorder_w_kernel(
    const float* __restrict__ W, unsigned short* __restrict__ WpHi,
    unsigned short* __restrict__ WpLo) {
    int i = blockIdx.x * 256 + threadIdx.x;  // 262144 threads
    int o = i & 63;
    int k = (i >> 6) & 511;
    int h = i >> 15;
    float v = W[i];
    unsigned short hi = f2bf(v);
    unsigned short lo = f2bf(v - bf2f(hi));
    long idx = (((h * 16) + (k >> 5)) * 64 + o) * 32 + (k & 31);
    WpHi[idx] = hi;
    WpLo[idx] = lo;
}

// ---------------------------------------------------------------------------
// GEMM1: Wh[h] = A[2048][512](f32) @ W[h][512][64], split-bf16 (3 MFMAs).
// 2-way K-split: block = 4 waves over (2 row-halves x 2 K-halves), 32 rows.
// Grid = 8 heads * 64 row-tiles = 512 blocks. LDS-reduce K partials.
// Epilogue (kw==0 waves): s1/s2 shfl-reduction + bf16 fragment-packed Whp.
// ---------------------------------------------------------------------------
__global__ __launch_bounds__(256, 2) void gemm1_kernel(
    const float* __restrict__ A,
    const unsigned short* __restrict__ BpHi, const unsigned short* __restrict__ BpLo,
    const float* __restrict__ avec,
    unsigned short* __restrict__ Whp, float* __restrict__ s1, float* __restrict__ s2) {
    __shared__ float accred[2][64][20];  // [rowhalf][col][16 rows + pad]
    const int bx   = blockIdx.x;   // 512
    const int h    = bx >> 6;
    const int mt   = bx & 63;
    const int tid  = threadIdx.x;
    const int wave = tid >> 6;
    const int lane = tid & 63;
    const int quad = lane >> 4;
    const int m16  = lane & 15;
    const int rw   = wave & 1;   // row half (16 rows each)
    const int kw   = wave >> 1;  // K half (256 each)
    const int rowbase = mt * 32 + rw * 16;

    const float* Arow = A + (long)(rowbase + m16) * 512 + kw * 256 + quad * 8;
    const long boff = ((long)(h * 16 + kw * 8) * 64 + m16) * 32 + quad * 8;
    const unsigned short* BH = BpHi + boff;
    const unsigned short* BL = BpLo + boff;

    f32x4 acc[4];
#pragma unroll
    for (int t = 0; t < 4; ++t)
#pragma unroll
        for (int r = 0; r < 4; ++r) acc[t][r] = 0.f;

    for (int kb = 0; kb < 8; ++kb) {
        const float* ap = Arow + kb * 32;
        bf16x8 ahi, alo;
#pragma unroll
        for (int j = 0; j < 8; ++j) {
            float v = ap[j];
            unsigned short hv = f2bf(v);
            ahi[j] = (short)hv;
            alo[j] = (short)f2bf(v - bf2f(hv));
        }
        const unsigned short* bh0 = BH + (long)kb * 2048;
        const unsigned short* bl0 = BL + (long)kb * 2048;
#pragma unroll
        for (int t = 0; t < 4; ++t) {
            bf16x8 bh = *reinterpret_cast<const bf16x8*>(bh0 + t * 512);
            bf16x8 bl = *reinterpret_cast<const bf16x8*>(bl0 + t * 512);
            acc[t] = __builtin_amdgcn_mfma_f32_16x16x32_bf16(alo, bh, acc[t], 0, 0, 0);
            acc[t] = __builtin_amdgcn_mfma_f32_16x16x32_bf16(ahi, bl, acc[t], 0, 0, 0);
            acc[t] = __builtin_amdgcn_mfma_f32_16x16x32_bf16(ahi, bh, acc[t], 0, 0, 0);
        }
    }

    if (kw == 1) {
#pragma unroll
        for (int t = 0; t < 4; ++t)
            *reinterpret_cast<f32x4*>(&accred[rw][t * 16 + m16][quad * 4]) = acc[t];
    }
    __syncthreads();
    if (kw == 1) return;

#pragma unroll
    for (int t = 0; t < 4; ++t) {
        f32x4 o = *reinterpret_cast<const f32x4*>(&accred[rw][t * 16 + m16][quad * 4]);
#pragma unroll
        for (int r = 0; r < 4; ++r) acc[t][r] += o[r];
    }

    // ---- s1/s2 epilogue ----
    float aS[4], aD[4];
#pragma unroll
    for (int t = 0; t < 4; ++t) {
        aS[t] = avec[(h << 7) + t * 16 + m16];
        aD[t] = avec[(h << 7) + 64 + t * 16 + m16];
    }
#pragma unroll
    for (int r = 0; r < 4; ++r) {
        float t1 = 0.f, t2 = 0.f;
#pragma unroll
        for (int t = 0; t < 4; ++t) {
            float v = acc[t][r];
            t1 = fmaf(v, aS[t], t1);
            t2 = fmaf(v, aD[t], t2);
        }
#pragma unroll
        for (int off = 1; off < 16; off <<= 1) {
            t1 += __shfl_xor(t1, off);
            t2 += __shfl_xor(t2, off);
        }
        if (m16 == 0) {
            int row = rowbase + quad * 4 + r;
            s1[(h << 11) + row] = t1;
            s2[(h << 11) + row] = t2;
        }
    }

    // ---- store Wh bf16 fragment-packed (Hi only; PV tolerates bf16) ----
#pragma unroll
    for (int t = 0; t < 4; ++t) {
        const int col = t * 16 + m16;
#pragma unroll
        for (int r = 0; r < 4; ++r) {
            const int row = rowbase + quad * 4 + r;
            long idx = (((long)(h * 64 + (row >> 5)) * 64 + col) << 5) + (row & 31);
            Whp[idx] = f2bf(acc[t][r]);
        }
    }
}

// ---------------------------------------------------------------------------
// Fused attention — HIGH-OCCUPANCY variant: 512 thr / 8 waves per block,
// each wave owns a j-EIGHTH (8 words). 1024 blocks -> 4 blocks/CU x 8 waves
// = 32 waves/CU (100%), targeting the latency-bound diagnosis (R10 counters:
// VALUBusy 9%, MfmaUtil 1%, HBM 7%, Occupancy 48% -> all pipes idle).
//  P12: online masked softmax scan; merge over 8 waves via LDS.
//  P3 : att write (per-wave LDS-staged packed NT full-line stores) + PV MFMA;
//       two-stage cross-wave PV reduction (fits 20.5KB union buffer).
// ---------------------------------------------------------------------------
__global__ __launch_bounds__(512, 8) void fused_att_kernel(
    const float* __restrict__ s1g, const float* __restrict__ s2g,
    const unsigned int* __restrict__ gbits,
    const unsigned short* __restrict__ Whp,
    float* __restrict__ att, float* __restrict__ hout) {
    __shared__ unsigned int lbits[16 * 65];   // 4160 B
    __shared__ float ls2[2048];               // 8192 B
    __shared__ float lmax[8][16];             // 512 B
    __shared__ float lsum[8][16];             // 512 B
    __shared__ __align__(16) char upool[20480];  // pstage[8][16][9] f32x4 (18432) | red[4][64][20] f32 (20480)
    f32x4 (*pstage)[16][9] = reinterpret_cast<f32x4(*)[16][9]>(upool);
    float (*red)[64][20]   = reinterpret_cast<float(*)[64][20]>(upool);

    const int bx   = blockIdx.x;   // 1024
    const int h    = bx >> 7;
    const int row0 = (bx & 127) << 4;
    const int tid  = threadIdx.x;  // 512
    const int wq   = tid >> 6;     // wave = j-eighth (0..7)
    const int lane = tid & 63;
    const int quad = lane >> 4;
    const int m16  = lane & 15;

    // stage adj bits (16 rows x 64 words) + s2 (2048 f32)
#pragma unroll
    for (int i = 0; i < 2; ++i) {
        int idx = i * 512 + tid;   // 1024 words
        lbits[(idx >> 6) * 65 + (idx & 63)] = gbits[((row0 + (idx >> 6)) << 6) + (idx & 63)];
    }
    reinterpret_cast<float4*>(ls2)[tid] =
        reinterpret_cast<const float4*>(s2g + (h << 11))[tid];   // 512 float4
    __syncthreads();

    const float s1i = s1g[(h << 11) + row0 + m16];

    // ---- P12: fused online masked max+sum over this wave's 8 words ----
    float mx = -INFINITY;
    float lp = 0.f;
    for (int i = 0; i < 8; ++i) {
        const int jt = wq * 8 + i;
        unsigned int word = lbits[m16 * 65 + jt] >> (quad * 8);
        float4 sa = *reinterpret_cast<const float4*>(ls2 + jt * 32 + quad * 8);
        float4 sb = *reinterpret_cast<const float4*>(ls2 + jt * 32 + quad * 8 + 4);
        float sv[8] = {sa.x, sa.y, sa.z, sa.w, sb.x, sb.y, sb.z, sb.w};
        float ev[8];
        float bm = -INFINITY;
#pragma unroll
        for (int u = 0; u < 8; ++u) {
            float e = s1i + sv[u];
            e = fmaxf(e, 0.2f * e);
            ev[u] = e;
            bm = fmaxf(bm, ((word >> u) & 1u) ? e : -INFINITY);
        }
        float nm = fmaxf(mx, bm);
        float sc = (mx == nm) ? 1.f : __expf(mx - nm);  // -inf==-inf -> 1 (no NaN)
        lp *= sc;
        mx = nm;
#pragma unroll
        for (int u = 0; u < 8; ++u)
            lp += ((word >> u) & 1u) ? __expf(ev[u] - mx) : 0.f;
    }
    // merge across the 4 quads of each row (lanes l, l^16, l^32, l^48)
#pragma unroll
    for (int off = 16; off < 64; off <<= 1) {
        float omx = __shfl_xor(mx, off);
        float olp = __shfl_xor(lp, off);
        float nm = fmaxf(mx, omx);
        float sa = (mx == nm) ? 1.f : __expf(mx - nm);
        float sb = (omx == nm) ? 1.f : __expf(omx - nm);
        lp = fmaf(lp, sa, olp * sb);
        mx = nm;
    }
    if (lane < 16) {
        lmax[wq][m16] = mx;
        lsum[wq][m16] = lp;
    }
    __syncthreads();
    // block-level merge over the 8 wave-eighths
    float m = lmax[0][m16];
#pragma unroll
    for (int w = 1; w < 8; ++w) m = fmaxf(m, lmax[w][m16]);
    float l = 0.f;
#pragma unroll
    for (int w = 0; w < 8; ++w) {
        float wm = lmax[w][m16];
        float ws = (wm == m) ? 1.f : __expf(wm - m);
        l = fmaf(lsum[w][m16], ws, l);
    }
    const bool am = (m == -INFINITY);          // all-masked row
    const float invl = am ? 0.f : 1.f / l;
    const float fallb = 1.f / 2048.f;

    // ---- P3: att write (LDS-staged, packed NT) + PV MFMA over j-eighth ----
    f32x4 acc[4];
#pragma unroll
    for (int t = 0; t < 4; ++t)
#pragma unroll
        for (int r = 0; r < 4; ++r) acc[t][r] = 0.f;

    const unsigned short* BW = Whp + ((long)(h << 12) + m16) * 32 + quad * 8;
    float* attbase = att + (long)h * 4194304 + (long)row0 * 2048;
    const int fr = lane >> 3;        // flush row within half (0..7)
    const int fc = lane & 7;         // flush col-block (16B units)

    for (int i = 0; i < 8; ++i) {
        const int jt = wq * 8 + i;
        unsigned int word = lbits[m16 * 65 + jt];
        float4 sa = *reinterpret_cast<const float4*>(ls2 + jt * 32 + quad * 8);
        float4 sb = *reinterpret_cast<const float4*>(ls2 + jt * 32 + quad * 8 + 4);
        float sv[8] = {sa.x, sa.y, sa.z, sa.w, sb.x, sb.y, sb.z, sb.w};
        float p[8];
        bf16x8 af;
#pragma unroll
        for (int u = 0; u < 8; ++u) {
            float e = s1i + sv[u];
            e = fmaxf(e, 0.2f * e);
            float pv = ((word >> (quad * 8 + u)) & 1u) ? __expf(e - m) * invl : 0.f;
            p[u] = am ? fallb : pv;
            af[u] = (short)f2bf(p[u]);
        }
        // stage P-tile (fragment layout -> row-major) in this wave's LDS region
        f32x4 plo, phi;
        plo[0] = p[0]; plo[1] = p[1]; plo[2] = p[2]; plo[3] = p[3];
        phi[0] = p[4]; phi[1] = p[5]; phi[2] = p[6]; phi[3] = p[7];
        pstage[wq][m16][quad * 2]     = plo;
        pstage[wq][m16][quad * 2 + 1] = phi;

        const unsigned short* b0 = BW + (long)jt * 2048;
#pragma unroll
        for (int t = 0; t < 4; ++t) {
            bf16x8 bf = *reinterpret_cast<const bf16x8*>(b0 + t * 512);
            acc[t] = __builtin_amdgcn_mfma_f32_16x16x32_bf16(af, bf, acc[t], 0, 0, 0);
        }

        // packed flush: 2 wave-stores, each 8 rows x 128B full lines (NT)
#pragma unroll
        for (int half = 0; half < 2; ++half) {
            const int r = half * 8 + fr;
            f32x4 v = pstage[wq][r][fc];
            __builtin_nontemporal_store(
                v, reinterpret_cast<f32x4*>(attbase + (long)r * 2048 + jt * 32 + fc * 4));
        }
    }

    // ---- two-stage cross-wave PV reduction (pool reuse barrier first) ----
    __syncthreads();          // all pstage reads retired
    if (wq >= 4) {
#pragma unroll
        for (int t = 0; t < 4; ++t)
            *reinterpret_cast<f32x4*>(&red[wq - 4][t * 16 + m16][quad * 4]) = acc[t];
    }
    __syncthreads();
    if (wq < 4) {
#pragma unroll
        for (int t = 0; t < 4; ++t) {
            f32x4 o = *reinterpret_cast<const f32x4*>(&red[wq][t * 16 + m16][quad * 4]);
#pragma unroll
            for (int r = 0; r < 4; ++r) acc[t][r] += o[r];
        }
    }
    __syncthreads();
    if (wq >= 1 && wq < 4) {
#pragma unroll
        for (int t = 0; t < 4; ++t)
            *reinterpret_cast<f32x4*>(&red[wq - 1][t * 16 + m16][quad * 4]) = acc[t];
    }
    __syncthreads();
    if (wq == 0) {
#pragma unroll
        for (int t = 0; t < 4; ++t) {
            const int col = t * 16 + m16;
#pragma unroll
            for (int w = 0; w < 3; ++w) {
                f32x4 o = *reinterpret_cast<const f32x4*>(&red[w][col][quad * 4]);
#pragma unroll
                for (int r = 0; r < 4; ++r) acc[t][r] += o[r];
            }
#pragma unroll
            for (int r = 0; r < 4; ++r) {
                const int row = row0 + quad * 4 + r;
                hout[(row << 9) + (h << 6) + col] = elu1(elu1(acc[t][r]));
            }
        }
    }
}

// ---------------------------------------------------------------------------
extern "C" void kernel_launch(void* const* d_in, const int* in_sizes, int n_in,
                              void* d_out, int out_size, void* d_ws, size_t ws_size,
                              hipStream_t stream) {
    const float* x  = (const float*)d_in[0];   // [2048][512]
    const int* adj  = (const int*)d_in[1];     // [2048][2048]
    const float* W1 = (const float*)d_in[2];   // [8][512][64]
    const float* a1 = (const float*)d_in[3];   // [8][128]
    const float* W2 = (const float*)d_in[4];
    const float* a2 = (const float*)d_in[5];

    float* out  = (float*)d_out;       // h2 [2048][512]
    float* att1 = out + 1048576;       // [8][2048][2048]
    float* att2 = att1 + 33554432;

    char* w = (char*)d_ws;
    unsigned short* Wp1Hi = (unsigned short*)(w);             // 512 KB
    unsigned short* Wp1Lo = (unsigned short*)(w + 524288);    // 512 KB
    unsigned short* Wp2Hi = (unsigned short*)(w + 1048576);   // 512 KB
    unsigned short* Wp2Lo = (unsigned short*)(w + 1572864);   // 512 KB
    unsigned short* Whp   = (unsigned short*)(w + 2097152);   // 2 MB
    float* s1             = (float*)(w + 4194304);            // 64 KB
    float* s2             = (float*)(w + 4259840);            // 64 KB
    unsigned long long* gbits = (unsigned long long*)(w + 4325376);  // 512 KB
    float* x2             = (float*)(w + 4849664);            // 4 MB -> ends ~8.6 MB

    const unsigned int* gbits32 = (const unsigned int*)gbits;

    // independent prep, all up front
    adjbits_kernel<<<16384, 256, 0, stream>>>(adj, gbits);
    reorder_w_kernel<<<1024, 256, 0, stream>>>(W1, Wp1Hi, Wp1Lo);
    reorder_w_kernel<<<1024, 256, 0, stream>>>(W2, Wp2Hi, Wp2Lo);

    // ---- layer 1 ----
    gemm1_kernel<<<512, 256, 0, stream>>>(x, Wp1Hi, Wp1Lo, a1, Whp, s1, s2);
    fused_att_kernel<<<1024, 512, 0, stream>>>(s1, s2, gbits32, Whp, att1, x2);

    // ---- layer 2 ----
    gemm1_kernel<<<512, 256, 0, stream>>>(x2, Wp2Hi, Wp2Lo, a2, Whp, s1, s2);
    fused_att_kernel<<<1024, 512, 0, stream>>>(s1, s2, gbits32, Whp, att2, out);
}

// Round 12
// 355.629 us; speedup vs baseline: 2.3186x; 1.0437x over previous
//
#include <hip/hip_runtime.h>
#include <hip/hip_bf16.h>

// GAT (2-layer, 8-head) on gfx950. Inputs f32 (adj int32), outputs f32.
// d_out = [h2: 2048*512 | att1: 8*2048*2048 | att2: 8*2048*2048] float32.

typedef __attribute__((ext_vector_type(8))) short bf16x8;
typedef __attribute__((ext_vector_type(4))) float f32x4;

__device__ __forceinline__ float bf2f(unsigned short u) {
    return __uint_as_float(((unsigned int)u) << 16);
}
__device__ __forceinline__ unsigned short f2bf(float f) {
    __hip_bfloat16 h = __float2bfloat16(f);
    return __builtin_bit_cast(unsigned short, h);
}
__device__ __forceinline__ float elu1(float x) { return x > 0.f ? x : expm1f(x); }

// ---------------------------------------------------------------------------
// adj [2048][2048] int32 -> bitmask [2048][64] u32 (u64 stores via ballot).
// ---------------------------------------------------------------------------
__global__ __launch_bounds__(256) void adjbits_kernel(
    const int* __restrict__ adj, unsigned long long* __restrict__ gbits) {
    int g = blockIdx.x * 256 + threadIdx.x;  // 4194304 threads
    unsigned long long m = __ballot(adj[g] > 0);
    if ((threadIdx.x & 63) == 0) gbits[g >> 6] = m;
}

// ---------------------------------------------------------------------------
// Reorder W [8][512][64] (f32) into split-bf16 MFMA B-fragment packing:
// Wp{Hi,Lo}[h][kb][col][k&31], k = kb*32 + (quad*8+j).
// ---------------------------------------------------------------------------
__global__ __launch_bounds__(256) void reorder_w_kernel(
    const float* __restrict__ W, unsigned short* __restrict__ WpHi,
    unsigned short* __restrict__ WpLo) {
    int i = blockIdx.x * 256 + threadIdx.x;  // 262144 threads
    int o = i & 63;
    int k = (i >> 6) & 511;
    int h = i >> 15;
    float v = W[i];
    unsigned short hi = f2bf(v);
    unsigned short lo = f2bf(v - bf2f(hi));
    long idx = (((h * 16) + (k >> 5)) * 64 + o) * 32 + (k & 31);
    WpHi[idx] = hi;
    WpLo[idx] = lo;
}

// ---------------------------------------------------------------------------
// GEMM1: Wh[h] = A[2048][512](f32) @ W[h][512][64], split-bf16 (3 MFMAs).
// 2-way K-split: block = 4 waves over (2 row-halves x 2 K-halves), 32 rows.
// Grid = 8 heads * 64 row-tiles = 512 blocks. LDS-reduce K partials.
// Epilogue (kw==0 waves): s1/s2 shfl-reduction + bf16 fragment-packed Whp.
// ---------------------------------------------------------------------------
__global__ __launch_bounds__(256, 2) void gemm1_kernel(
    const float* __restrict__ A,
    const unsigned short* __restrict__ BpHi, const unsigned short* __restrict__ BpLo,
    const float* __restrict__ avec,
    unsigned short* __restrict__ Whp, float* __restrict__ s1, float* __restrict__ s2) {
    __shared__ float accred[2][64][20];  // [rowhalf][col][16 rows + pad]
    const int bx   = blockIdx.x;   // 512
    const int h    = bx >> 6;
    const int mt   = bx & 63;
    const int tid  = threadIdx.x;
    const int wave = tid >> 6;
    const int lane = tid & 63;
    const int quad = lane >> 4;
    const int m16  = lane & 15;
    const int rw   = wave & 1;   // row half (16 rows each)
    const int kw   = wave >> 1;  // K half (256 each)
    const int rowbase = mt * 32 + rw * 16;

    const float* Arow = A + (long)(rowbase + m16) * 512 + kw * 256 + quad * 8;
    const long boff = ((long)(h * 16 + kw * 8) * 64 + m16) * 32 + quad * 8;
    const unsigned short* BH = BpHi + boff;
    const unsigned short* BL = BpLo + boff;

    f32x4 acc[4];
#pragma unroll
    for (int t = 0; t < 4; ++t)
#pragma unroll
        for (int r = 0; r < 4; ++r) acc[t][r] = 0.f;

    for (int kb = 0; kb < 8; ++kb) {
        const float* ap = Arow + kb * 32;
        bf16x8 ahi, alo;
#pragma unroll
        for (int j = 0; j < 8; ++j) {
            float v = ap[j];
            unsigned short hv = f2bf(v);
            ahi[j] = (short)hv;
            alo[j] = (short)f2bf(v - bf2f(hv));
        }
        const unsigned short* bh0 = BH + (long)kb * 2048;
        const unsigned short* bl0 = BL + (long)kb * 2048;
#pragma unroll
        for (int t = 0; t < 4; ++t) {
            bf16x8 bh = *reinterpret_cast<const bf16x8*>(bh0 + t * 512);
            bf16x8 bl = *reinterpret_cast<const bf16x8*>(bl0 + t * 512);
            acc[t] = __builtin_amdgcn_mfma_f32_16x16x32_bf16(alo, bh, acc[t], 0, 0, 0);
            acc[t] = __builtin_amdgcn_mfma_f32_16x16x32_bf16(ahi, bl, acc[t], 0, 0, 0);
            acc[t] = __builtin_amdgcn_mfma_f32_16x16x32_bf16(ahi, bh, acc[t], 0, 0, 0);
        }
    }

    if (kw == 1) {
#pragma unroll
        for (int t = 0; t < 4; ++t)
            *reinterpret_cast<f32x4*>(&accred[rw][t * 16 + m16][quad * 4]) = acc[t];
    }
    __syncthreads();
    if (kw == 1) return;

#pragma unroll
    for (int t = 0; t < 4; ++t) {
        f32x4 o = *reinterpret_cast<const f32x4*>(&accred[rw][t * 16 + m16][quad * 4]);
#pragma unroll
        for (int r = 0; r < 4; ++r) acc[t][r] += o[r];
    }

    // ---- s1/s2 epilogue ----
    float aS[4], aD[4];
#pragma unroll
    for (int t = 0; t < 4; ++t) {
        aS[t] = avec[(h << 7) + t * 16 + m16];
        aD[t] = avec[(h << 7) + 64 + t * 16 + m16];
    }
#pragma unroll
    for (int r = 0; r < 4; ++r) {
        float t1 = 0.f, t2 = 0.f;
#pragma unroll
        for (int t = 0; t < 4; ++t) {
            float v = acc[t][r];
            t1 = fmaf(v, aS[t], t1);
            t2 = fmaf(v, aD[t], t2);
        }
#pragma unroll
        for (int off = 1; off < 16; off <<= 1) {
            t1 += __shfl_xor(t1, off);
            t2 += __shfl_xor(t2, off);
        }
        if (m16 == 0) {
            int row = rowbase + quad * 4 + r;
            s1[(h << 11) + row] = t1;
            s2[(h << 11) + row] = t2;
        }
    }

    // ---- store Wh bf16 fragment-packed (Hi only; PV tolerates bf16) ----
#pragma unroll
    for (int t = 0; t < 4; ++t) {
        const int col = t * 16 + m16;
#pragma unroll
        for (int r = 0; r < 4; ++r) {
            const int row = rowbase + quad * 4 + r;
            long idx = (((long)(h * 64 + (row >> 5)) * 64 + col) << 5) + (row & 31);
            Whp[idx] = f2bf(acc[t][r]);
        }
    }
}

// ---------------------------------------------------------------------------
// Fused attention, 2 passes (R3/R4 structure = empirical best 358.5us):
//  P12: ONLINE masked softmax scan (exact per-row max + sum in one pass).
//  P3 : stage -> FLUSH (NT stores issued BEFORE the MFMA cluster so the
//       store stream is in flight during MFMA execution) -> PV MFMA.
// Block = 256 thr (4 waves), 16 rows; each wave owns a j-quarter.
// ---------------------------------------------------------------------------
__global__ __launch_bounds__(256, 4) void fused_att_kernel(
    const float* __restrict__ s1g, const float* __restrict__ s2g,
    const unsigned int* __restrict__ gbits,
    const unsigned short* __restrict__ Whp,
    float* __restrict__ att, float* __restrict__ hout) {
    __shared__ unsigned int lbits[16 * 65];   // 16 rows x 64 words, +1 pad
    __shared__ float ls2[2048];
    __shared__ float lmax[4][16];
    __shared__ float lsum[4][16];
    __shared__ float accred[3][64][20];       // waves 1..3 partial PV
    __shared__ f32x4 pstage[4][16][9];        // per-wave P staging

    const int bx   = blockIdx.x;   // 1024
    const int h    = bx >> 7;
    const int row0 = (bx & 127) << 4;
    const int tid  = threadIdx.x;
    const int wq   = tid >> 6;     // wave = j-quarter
    const int lane = tid & 63;
    const int quad = lane >> 4;
    const int m16  = lane & 15;

    // stage adj bits (16 rows x 64 words) + s2 (2048 f32)
#pragma unroll
    for (int i = 0; i < 4; ++i) {
        int idx = i * 256 + tid;
        lbits[(idx >> 6) * 65 + (idx & 63)] = gbits[((row0 + (idx >> 6)) << 6) + (idx & 63)];
    }
    const float4* s2v4 = reinterpret_cast<const float4*>(s2g + (h << 11));
#pragma unroll
    for (int i = 0; i < 2; ++i) {
        int idx = i * 256 + tid;
        reinterpret_cast<float4*>(ls2)[idx] = s2v4[idx];
    }
    __syncthreads();

    const float s1i = s1g[(h << 11) + row0 + m16];

    // ---- P12: fused online masked max+sum over this wave's 16 words ----
    float mx = -INFINITY;
    float lp = 0.f;
#pragma unroll 2
    for (int i = 0; i < 16; ++i) {
        const int jt = wq * 16 + i;
        unsigned int word = lbits[m16 * 65 + jt] >> (quad * 8);
        float4 sa = *reinterpret_cast<const float4*>(ls2 + jt * 32 + quad * 8);
        float4 sb = *reinterpret_cast<const float4*>(ls2 + jt * 32 + quad * 8 + 4);
        float sv[8] = {sa.x, sa.y, sa.z, sa.w, sb.x, sb.y, sb.z, sb.w};
        float ev[8];
        float bm = -INFINITY;
#pragma unroll
        for (int u = 0; u < 8; ++u) {
            float e = s1i + sv[u];
            e = fmaxf(e, 0.2f * e);
            ev[u] = e;
            bm = fmaxf(bm, ((word >> u) & 1u) ? e : -INFINITY);
        }
        float nm = fmaxf(mx, bm);
        float sc = (mx == nm) ? 1.f : __expf(mx - nm);  // -inf==-inf -> 1 (no NaN)
        lp *= sc;
        mx = nm;
#pragma unroll
        for (int u = 0; u < 8; ++u)
            lp += ((word >> u) & 1u) ? __expf(ev[u] - mx) : 0.f;
    }
    // merge across the 4 quads of each row (lanes l, l^16, l^32, l^48)
#pragma unroll
    for (int off = 16; off < 64; off <<= 1) {
        float omx = __shfl_xor(mx, off);
        float olp = __shfl_xor(lp, off);
        float nm = fmaxf(mx, omx);
        float sa = (mx == nm) ? 1.f : __expf(mx - nm);
        float sb = (omx == nm) ? 1.f : __expf(omx - nm);
        lp = fmaf(lp, sa, olp * sb);
        mx = nm;
    }
    if (lane < 16) {
        lmax[wq][m16] = mx;
        lsum[wq][m16] = lp;
    }
    __syncthreads();
    // block-level merge over the 4 wave-quarters
    float m = fmaxf(fmaxf(lmax[0][m16], lmax[1][m16]),
                    fmaxf(lmax[2][m16], lmax[3][m16]));
    float l = 0.f;
#pragma unroll
    for (int w = 0; w < 4; ++w) {
        float wm = lmax[w][m16];
        float ws = (wm == m) ? 1.f : __expf(wm - m);
        l = fmaf(lsum[w][m16], ws, l);
    }
    const bool am = (m == -INFINITY);          // all-masked row
    const float invl = am ? 0.f : 1.f / l;
    const float fallb = 1.f / 2048.f;

    // ---- P3: att write (stage -> flush -> MFMA; stores lead compute) ----
    f32x4 acc[4];
#pragma unroll
    for (int t = 0; t < 4; ++t)
#pragma unroll
        for (int r = 0; r < 4; ++r) acc[t][r] = 0.f;

    const unsigned short* BW = Whp + ((long)(h << 12) + m16) * 32 + quad * 8;
    float* attbase = att + (long)h * 4194304 + (long)row0 * 2048;
    const int fr = lane >> 3;        // flush row within half (0..7)
    const int fc = lane & 7;         // flush col-block (16B units)

#pragma unroll 2
    for (int i = 0; i < 16; ++i) {
        const int jt = wq * 16 + i;
        unsigned int word = lbits[m16 * 65 + jt];
        float4 sa = *reinterpret_cast<const float4*>(ls2 + jt * 32 + quad * 8);
        float4 sb = *reinterpret_cast<const float4*>(ls2 + jt * 32 + quad * 8 + 4);
        float sv[8] = {sa.x, sa.y, sa.z, sa.w, sb.x, sb.y, sb.z, sb.w};
        float p[8];
        bf16x8 af;
#pragma unroll
        for (int u = 0; u < 8; ++u) {
            float e = s1i + sv[u];
            e = fmaxf(e, 0.2f * e);
            float pv = ((word >> (quad * 8 + u)) & 1u) ? __expf(e - m) * invl : 0.f;
            p[u] = am ? fallb : pv;
            af[u] = (short)f2bf(p[u]);
        }
        // stage P-tile (fragment layout -> row-major) in this wave's LDS region
        f32x4 plo, phi;
        plo[0] = p[0]; plo[1] = p[1]; plo[2] = p[2]; plo[3] = p[3];
        phi[0] = p[4]; phi[1] = p[5]; phi[2] = p[6]; phi[3] = p[7];
        pstage[wq][m16][quad * 2]     = plo;
        pstage[wq][m16][quad * 2 + 1] = phi;

        // packed flush FIRST (within-wave LDS RAW; lgkmcnt-ordered, no barrier):
        // 2 wave-stores, each 8 rows x 128B full lines (NT) — in flight during MFMA
#pragma unroll
        for (int half = 0; half < 2; ++half) {
            const int r = half * 8 + fr;
            f32x4 v = pstage[wq][r][fc];
            __builtin_nontemporal_store(
                v, reinterpret_cast<f32x4*>(attbase + (long)r * 2048 + jt * 32 + fc * 4));
        }

        const unsigned short* b0 = BW + (long)jt * 2048;
#pragma unroll
        for (int t = 0; t < 4; ++t) {
            bf16x8 bf = *reinterpret_cast<const bf16x8*>(b0 + t * 512);
            acc[t] = __builtin_amdgcn_mfma_f32_16x16x32_bf16(af, bf, acc[t], 0, 0, 0);
        }
    }

    // ---- reduce partial PV across waves, epilogue by wave 0 ----
    if (wq > 0) {
#pragma unroll
        for (int t = 0; t < 4; ++t)
            *reinterpret_cast<f32x4*>(&accred[wq - 1][t * 16 + m16][quad * 4]) = acc[t];
    }
    __syncthreads();
    if (wq == 0) {
#pragma unroll
        for (int t = 0; t < 4; ++t) {
            const int col = t * 16 + m16;
#pragma unroll
            for (int w = 0; w < 3; ++w) {
                f32x4 o = *reinterpret_cast<const f32x4*>(&accred[w][col][quad * 4]);
#pragma unroll
                for (int r = 0; r < 4; ++r) acc[t][r] += o[r];
            }
#pragma unroll
            for (int r = 0; r < 4; ++r) {
                const int row = row0 + quad * 4 + r;
                hout[(row << 9) + (h << 6) + col] = elu1(elu1(acc[t][r]));
            }
        }
    }
}

// ---------------------------------------------------------------------------
extern "C" void kernel_launch(void* const* d_in, const int* in_sizes, int n_in,
                              void* d_out, int out_size, void* d_ws, size_t ws_size,
                              hipStream_t stream) {
    const float* x  = (const float*)d_in[0];   // [2048][512]
    const int* adj  = (const int*)d_in[1];     // [2048][2048]
    const float* W1 = (const float*)d_in[2];   // [8][512][64]
    const float* a1 = (const float*)d_in[3];   // [8][128]
    const float* W2 = (const float*)d_in[4];
    const float* a2 = (const float*)d_in[5];

    float* out  = (float*)d_out;       // h2 [2048][512]
    float* att1 = out + 1048576;       // [8][2048][2048]
    float* att2 = att1 + 33554432;

    char* w = (char*)d_ws;
    unsigned short* Wp1Hi = (unsigned short*)(w);             // 512 KB
    unsigned short* Wp1Lo = (unsigned short*)(w + 524288);    // 512 KB
    unsigned short* Wp2Hi = (unsigned short*)(w + 1048576);   // 512 KB
    unsigned short* Wp2Lo = (unsigned short*)(w + 1572864);   // 512 KB
    unsigned short* Whp   = (unsigned short*)(w + 2097152);   // 2 MB
    float* s1             = (float*)(w + 4194304);            // 64 KB
    float* s2             = (float*)(w + 4259840);            // 64 KB
    unsigned long long* gbits = (unsigned long long*)(w + 4325376);  // 512 KB
    float* x2             = (float*)(w + 4849664);            // 4 MB -> ends ~8.6 MB

    const unsigned int* gbits32 = (const unsigned int*)gbits;

    // independent prep, all up front
    adjbits_kernel<<<16384, 256, 0, stream>>>(adj, gbits);
    reorder_w_kernel<<<1024, 256, 0, stream>>>(W1, Wp1Hi, Wp1Lo);
    reorder_w_kernel<<<1024, 256, 0, stream>>>(W2, Wp2Hi, Wp2Lo);

    // ---- layer 1 ----
    gemm1_kernel<<<512, 256, 0, stream>>>(x, Wp1Hi, Wp1Lo, a1, Whp, s1, s2);
    fused_att_kernel<<<1024, 256, 0, stream>>>(s1, s2, gbits32, Whp, att1, x2);

    // ---- layer 2 ----
    gemm1_kernel<<<512, 256, 0, stream>>>(x2, Wp2Hi, Wp2Lo, a2, Whp, s1, s2);
    fused_att_kernel<<<1024, 256, 0, stream>>>(s1, s2, gbits32, Whp, att2, out);
}

// Round 13
// 349.563 us; speedup vs baseline: 2.3589x; 1.0174x over previous
//
#include <hip/hip_runtime.h>
#include <hip/hip_bf16.h>

// GAT (2-layer, 8-head) on gfx950. Inputs f32 (adj int32), outputs f32.
// d_out = [h2: 2048*512 | att1: 8*2048*2048 | att2: 8*2048*2048] float32.

typedef __attribute__((ext_vector_type(8))) short bf16x8;
typedef __attribute__((ext_vector_type(4))) float f32x4;

__device__ __forceinline__ float bf2f(unsigned short u) {
    return __uint_as_float(((unsigned int)u) << 16);
}
__device__ __forceinline__ unsigned short f2bf(float f) {
    __hip_bfloat16 h = __float2bfloat16(f);
    return __builtin_bit_cast(unsigned short, h);
}
__device__ __forceinline__ float elu1(float x) { return x > 0.f ? x : expm1f(x); }

// ---------------------------------------------------------------------------
// Merged prep: grid 3072 x 256.
//  blocks [0,2048): adjbits — adj int32 -> bitmask, int4-vectorized,
//                   2 rows' worth per block (grid-stride by 4 words/lane).
//  blocks [2048,3072): reorder W1 AND W2 -> split-bf16 MFMA B-fragment packing
//                   Wp{Hi,Lo}[h][kb][col][k&31], k = kb*32 + (quad*8+j).
// ---------------------------------------------------------------------------
__global__ __launch_bounds__(256) void prep_kernel(
    const int* __restrict__ adj, unsigned long long* __restrict__ gbits,
    const float* __restrict__ W1, unsigned short* __restrict__ Wp1Hi,
    unsigned short* __restrict__ Wp1Lo,
    const float* __restrict__ W2, unsigned short* __restrict__ Wp2Hi,
    unsigned short* __restrict__ Wp2Lo) {
    const int bx  = blockIdx.x;
    const int tid = threadIdx.x;
    if (bx < 2048) {
        // 2048 blocks x 256 thr x 8 elems = 4194304 adj entries
        const int4* adj4 = reinterpret_cast<const int4*>(adj);
#pragma unroll
        for (int i = 0; i < 2; ++i) {
            int g4 = (bx * 512) + i * 256 + tid;        // int4 index
            int4 v = adj4[g4];
            // each lane holds 4 consecutive entries; build 64-lane ballots
            // for the 4 interleaved sub-words then scatter: entries 4g..4g+3.
            // Simpler: process as 4 scalar ballots on strided lanes is wrong;
            // instead re-derive per-entry predicate and pack via 4 ballots,
            // each covering entries with (idx&3)==c for this lane group —
            // but ballots are lane-indexed, so do it the direct way:
            unsigned long long b0 = __ballot(v.x > 0);
            unsigned long long b1 = __ballot(v.y > 0);
            unsigned long long b2 = __ballot(v.z > 0);
            unsigned long long b3 = __ballot(v.w > 0);
            // lane L's 4 entries are 4*(g4) .. 4*g4+3 -> entry index e = 4*(base+L)+c.
            // word w = e>>6; within a 64-lane group, entries span 4 words:
            // word j (j=0..3) holds entries where (L>>4)==j ... reconstruct:
            // entry e = (base*4) + 4L + c ; e>>6 = base/16 + (4L+c)/64.
            // Pack per 16-lane quarter: word q covers lanes q*16..q*16+15.
            if ((tid & 63) == 0) {
                int lane0 = 0;  // this wave's first lane
                (void)lane0;
            }
            // Build the 4 output words from the 4 ballots: word q's bit (4l+c)
            // (l=0..15) = ballot_c bit (q*16+l).
            int wave = tid >> 6;
            int lane = tid & 63;
            if (lane < 4) {
                int q = lane;   // word index within this wave's 4 words
                unsigned long long w0 = 0;
#pragma unroll
                for (int l = 0; l < 16; ++l) {
                    unsigned long long bit;
                    bit = (b0 >> (q * 16 + l)) & 1ull; w0 |= bit << (4 * l + 0);
                    bit = (b1 >> (q * 16 + l)) & 1ull; w0 |= bit << (4 * l + 1);
                    bit = (b2 >> (q * 16 + l)) & 1ull; w0 |= bit << (4 * l + 2);
                    bit = (b3 >> (q * 16 + l)) & 1ull; w0 |= bit << (4 * l + 3);
                }
                // first entry of this wave = 4*(bx*512 + i*256 + wave*64)
                long ebase = 4L * (bx * 512 + i * 256 + wave * 64);
                gbits[(ebase >> 6) + q] = w0;
            }
        }
    } else {
        int i = (bx - 2048) * 256 + tid;  // 262144 threads, one elem each
        int o = i & 63;
        int k = (i >> 6) & 511;
        int h = i >> 15;
        long idx = (((h * 16) + (k >> 5)) * 64 + o) * 32 + (k & 31);
        float v1 = W1[i];
        unsigned short h1 = f2bf(v1);
        Wp1Hi[idx] = h1;
        Wp1Lo[idx] = f2bf(v1 - bf2f(h1));
        float v2 = W2[i];
        unsigned short h2 = f2bf(v2);
        Wp2Hi[idx] = h2;
        Wp2Lo[idx] = f2bf(v2 - bf2f(h2));
    }
}

// ---------------------------------------------------------------------------
// GEMM1: Wh[h] = A[2048][512](f32) @ W[h][512][64], split-bf16 (3 MFMAs).
// 2-way K-split: block = 4 waves over (2 row-halves x 2 K-halves), 32 rows.
// Grid = 8 heads * 64 row-tiles = 512 blocks. LDS-reduce K partials.
// Epilogue (kw==0 waves): s1/s2 shfl-reduction + bf16 fragment-packed Whp.
// ---------------------------------------------------------------------------
__global__ __launch_bounds__(256, 2) void gemm1_kernel(
    const float* __restrict__ A,
    const unsigned short* __restrict__ BpHi, const unsigned short* __restrict__ BpLo,
    const float* __restrict__ avec,
    unsigned short* __restrict__ Whp, float* __restrict__ s1, float* __restrict__ s2) {
    __shared__ float accred[2][64][20];  // [rowhalf][col][16 rows + pad]
    const int bx   = blockIdx.x;   // 512
    const int h    = bx >> 6;
    const int mt   = bx & 63;
    const int tid  = threadIdx.x;
    const int wave = tid >> 6;
    const int lane = tid & 63;
    const int quad = lane >> 4;
    const int m16  = lane & 15;
    const int rw   = wave & 1;   // row half (16 rows each)
    const int kw   = wave >> 1;  // K half (256 each)
    const int rowbase = mt * 32 + rw * 16;

    const float* Arow = A + (long)(rowbase + m16) * 512 + kw * 256 + quad * 8;
    const long boff = ((long)(h * 16 + kw * 8) * 64 + m16) * 32 + quad * 8;
    const unsigned short* BH = BpHi + boff;
    const unsigned short* BL = BpLo + boff;

    f32x4 acc[4];
#pragma unroll
    for (int t = 0; t < 4; ++t)
#pragma unroll
        for (int r = 0; r < 4; ++r) acc[t][r] = 0.f;

    for (int kb = 0; kb < 8; ++kb) {
        const float* ap = Arow + kb * 32;
        bf16x8 ahi, alo;
#pragma unroll
        for (int j = 0; j < 8; ++j) {
            float v = ap[j];
            unsigned short hv = f2bf(v);
            ahi[j] = (short)hv;
            alo[j] = (short)f2bf(v - bf2f(hv));
        }
        const unsigned short* bh0 = BH + (long)kb * 2048;
        const unsigned short* bl0 = BL + (long)kb * 2048;
#pragma unroll
        for (int t = 0; t < 4; ++t) {
            bf16x8 bh = *reinterpret_cast<const bf16x8*>(bh0 + t * 512);
            bf16x8 bl = *reinterpret_cast<const bf16x8*>(bl0 + t * 512);
            acc[t] = __builtin_amdgcn_mfma_f32_16x16x32_bf16(alo, bh, acc[t], 0, 0, 0);
            acc[t] = __builtin_amdgcn_mfma_f32_16x16x32_bf16(ahi, bl, acc[t], 0, 0, 0);
            acc[t] = __builtin_amdgcn_mfma_f32_16x16x32_bf16(ahi, bh, acc[t], 0, 0, 0);
        }
    }

    if (kw == 1) {
#pragma unroll
        for (int t = 0; t < 4; ++t)
            *reinterpret_cast<f32x4*>(&accred[rw][t * 16 + m16][quad * 4]) = acc[t];
    }
    __syncthreads();
    if (kw == 1) return;

#pragma unroll
    for (int t = 0; t < 4; ++t) {
        f32x4 o = *reinterpret_cast<const f32x4*>(&accred[rw][t * 16 + m16][quad * 4]);
#pragma unroll
        for (int r = 0; r < 4; ++r) acc[t][r] += o[r];
    }

    // ---- s1/s2 epilogue ----
    float aS[4], aD[4];
#pragma unroll
    for (int t = 0; t < 4; ++t) {
        aS[t] = avec[(h << 7) + t * 16 + m16];
        aD[t] = avec[(h << 7) + 64 + t * 16 + m16];
    }
#pragma unroll
    for (int r = 0; r < 4; ++r) {
        float t1 = 0.f, t2 = 0.f;
#pragma unroll
        for (int t = 0; t < 4; ++t) {
            float v = acc[t][r];
            t1 = fmaf(v, aS[t], t1);
            t2 = fmaf(v, aD[t], t2);
        }
#pragma unroll
        for (int off = 1; off < 16; off <<= 1) {
            t1 += __shfl_xor(t1, off);
            t2 += __shfl_xor(t2, off);
        }
        if (m16 == 0) {
            int row = rowbase + quad * 4 + r;
            s1[(h << 11) + row] = t1;
            s2[(h << 11) + row] = t2;
        }
    }

    // ---- store Wh bf16 fragment-packed (Hi only; PV tolerates bf16) ----
#pragma unroll
    for (int t = 0; t < 4; ++t) {
        const int col = t * 16 + m16;
#pragma unroll
        for (int r = 0; r < 4; ++r) {
            const int row = rowbase + quad * 4 + r;
            long idx = (((long)(h * 64 + (row >> 5)) * 64 + col) << 5) + (row & 31);
            Whp[idx] = f2bf(acc[t][r]);
        }
    }
}

// ---------------------------------------------------------------------------
// Fused attention, 2 passes (R12 structure = empirical best 355.6us):
//  P12: ONLINE masked softmax scan (exact per-row max + sum in one pass).
//  P3 : stage -> FLUSH (NT stores lead the MFMA cluster) -> PV MFMA.
// Block = 256 thr (4 waves), 16 rows; each wave owns a j-quarter.
// ---------------------------------------------------------------------------
__global__ __launch_bounds__(256, 4) void fused_att_kernel(
    const float* __restrict__ s1g, const float* __restrict__ s2g,
    const unsigned int* __restrict__ gbits,
    const unsigned short* __restrict__ Whp,
    float* __restrict__ att, float* __restrict__ hout) {
    __shared__ unsigned int lbits[16 * 65];   // 16 rows x 64 words, +1 pad
    __shared__ float ls2[2048];
    __shared__ float lmax[4][16];
    __shared__ float lsum[4][16];
    __shared__ float accred[3][64][20];       // waves 1..3 partial PV
    __shared__ f32x4 pstage[4][16][9];        // per-wave P staging

    const int bx   = blockIdx.x;   // 1024
    const int h    = bx >> 7;
    const int row0 = (bx & 127) << 4;
    const int tid  = threadIdx.x;
    const int wq   = tid >> 6;     // wave = j-quarter
    const int lane = tid & 63;
    const int quad = lane >> 4;
    const int m16  = lane & 15;

    // stage adj bits (16 rows x 64 words) + s2 (2048 f32)
#pragma unroll
    for (int i = 0; i < 4; ++i) {
        int idx = i * 256 + tid;
        lbits[(idx >> 6) * 65 + (idx & 63)] = gbits[((row0 + (idx >> 6)) << 6) + (idx & 63)];
    }
    const float4* s2v4 = reinterpret_cast<const float4*>(s2g + (h << 11));
#pragma unroll
    for (int i = 0; i < 2; ++i) {
        int idx = i * 256 + tid;
        reinterpret_cast<float4*>(ls2)[idx] = s2v4[idx];
    }
    __syncthreads();

    const float s1i = s1g[(h << 11) + row0 + m16];

    // ---- P12: fused online masked max+sum over this wave's 16 words ----
    float mx = -INFINITY;
    float lp = 0.f;
#pragma unroll 2
    for (int i = 0; i < 16; ++i) {
        const int jt = wq * 16 + i;
        unsigned int word = lbits[m16 * 65 + jt] >> (quad * 8);
        float4 sa = *reinterpret_cast<const float4*>(ls2 + jt * 32 + quad * 8);
        float4 sb = *reinterpret_cast<const float4*>(ls2 + jt * 32 + quad * 8 + 4);
        float sv[8] = {sa.x, sa.y, sa.z, sa.w, sb.x, sb.y, sb.z, sb.w};
        float ev[8];
        float bm = -INFINITY;
#pragma unroll
        for (int u = 0; u < 8; ++u) {
            float e = s1i + sv[u];
            e = fmaxf(e, 0.2f * e);
            ev[u] = e;
            bm = fmaxf(bm, ((word >> u) & 1u) ? e : -INFINITY);
        }
        float nm = fmaxf(mx, bm);
        float sc = (mx == nm) ? 1.f : __expf(mx - nm);  // -inf==-inf -> 1 (no NaN)
        lp *= sc;
        mx = nm;
#pragma unroll
        for (int u = 0; u < 8; ++u)
            lp += ((word >> u) & 1u) ? __expf(ev[u] - mx) : 0.f;
    }
    // merge across the 4 quads of each row (lanes l, l^16, l^32, l^48)
#pragma unroll
    for (int off = 16; off < 64; off <<= 1) {
        float omx = __shfl_xor(mx, off);
        float olp = __shfl_xor(lp, off);
        float nm = fmaxf(mx, omx);
        float sa = (mx == nm) ? 1.f : __expf(mx - nm);
        float sb = (omx == nm) ? 1.f : __expf(omx - nm);
        lp = fmaf(lp, sa, olp * sb);
        mx = nm;
    }
    if (lane < 16) {
        lmax[wq][m16] = mx;
        lsum[wq][m16] = lp;
    }
    __syncthreads();
    // block-level merge over the 4 wave-quarters
    float m = fmaxf(fmaxf(lmax[0][m16], lmax[1][m16]),
                    fmaxf(lmax[2][m16], lmax[3][m16]));
    float l = 0.f;
#pragma unroll
    for (int w = 0; w < 4; ++w) {
        float wm = lmax[w][m16];
        float ws = (wm == m) ? 1.f : __expf(wm - m);
        l = fmaf(lsum[w][m16], ws, l);
    }
    const bool am = (m == -INFINITY);          // all-masked row
    const float invl = am ? 0.f : 1.f / l;
    const float fallb = 1.f / 2048.f;

    // ---- P3: att write (stage -> flush -> MFMA; stores lead compute) ----
    f32x4 acc[4];
#pragma unroll
    for (int t = 0; t < 4; ++t)
#pragma unroll
        for (int r = 0; r < 4; ++r) acc[t][r] = 0.f;

    const unsigned short* BW = Whp + ((long)(h << 12) + m16) * 32 + quad * 8;
    float* attbase = att + (long)h * 4194304 + (long)row0 * 2048;
    const int fr = lane >> 3;        // flush row within half (0..7)
    const int fc = lane & 7;         // flush col-block (16B units)

#pragma unroll 2
    for (int i = 0; i < 16; ++i) {
        const int jt = wq * 16 + i;
        unsigned int word = lbits[m16 * 65 + jt];
        float4 sa = *reinterpret_cast<const float4*>(ls2 + jt * 32 + quad * 8);
        float4 sb = *reinterpret_cast<const float4*>(ls2 + jt * 32 + quad * 8 + 4);
        float sv[8] = {sa.x, sa.y, sa.z, sa.w, sb.x, sb.y, sb.z, sb.w};
        float p[8];
        bf16x8 af;
#pragma unroll
        for (int u = 0; u < 8; ++u) {
            float e = s1i + sv[u];
            e = fmaxf(e, 0.2f * e);
            float pv = ((word >> (quad * 8 + u)) & 1u) ? __expf(e - m) * invl : 0.f;
            p[u] = am ? fallb : pv;
            af[u] = (short)f2bf(p[u]);
        }
        // stage P-tile (fragment layout -> row-major) in this wave's LDS region
        f32x4 plo, phi;
        plo[0] = p[0]; plo[1] = p[1]; plo[2] = p[2]; plo[3] = p[3];
        phi[0] = p[4]; phi[1] = p[5]; phi[2] = p[6]; phi[3] = p[7];
        pstage[wq][m16][quad * 2]     = plo;
        pstage[wq][m16][quad * 2 + 1] = phi;

        // packed flush FIRST (within-wave LDS RAW; lgkmcnt-ordered, no barrier):
        // 2 wave-stores, each 8 rows x 128B full lines (NT) — in flight during MFMA
#pragma unroll
        for (int half = 0; half < 2; ++half) {
            const int r = half * 8 + fr;
            f32x4 v = pstage[wq][r][fc];
            __builtin_nontemporal_store(
                v, reinterpret_cast<f32x4*>(attbase + (long)r * 2048 + jt * 32 + fc * 4));
        }

        const unsigned short* b0 = BW + (long)jt * 2048;
#pragma unroll
        for (int t = 0; t < 4; ++t) {
            bf16x8 bf = *reinterpret_cast<const bf16x8*>(b0 + t * 512);
            acc[t] = __builtin_amdgcn_mfma_f32_16x16x32_bf16(af, bf, acc[t], 0, 0, 0);
        }
    }

    // ---- reduce partial PV across waves, epilogue by wave 0 ----
    if (wq > 0) {
#pragma unroll
        for (int t = 0; t < 4; ++t)
            *reinterpret_cast<f32x4*>(&accred[wq - 1][t * 16 + m16][quad * 4]) = acc[t];
    }
    __syncthreads();
    if (wq == 0) {
#pragma unroll
        for (int t = 0; t < 4; ++t) {
            const int col = t * 16 + m16;
#pragma unroll
            for (int w = 0; w < 3; ++w) {
                f32x4 o = *reinterpret_cast<const f32x4*>(&accred[w][col][quad * 4]);
#pragma unroll
                for (int r = 0; r < 4; ++r) acc[t][r] += o[r];
            }
#pragma unroll
            for (int r = 0; r < 4; ++r) {
                const int row = row0 + quad * 4 + r;
                hout[(row << 9) + (h << 6) + col] = elu1(elu1(acc[t][r]));
            }
        }
    }
}

// ---------------------------------------------------------------------------
extern "C" void kernel_launch(void* const* d_in, const int* in_sizes, int n_in,
                              void* d_out, int out_size, void* d_ws, size_t ws_size,
                              hipStream_t stream) {
    const float* x  = (const float*)d_in[0];   // [2048][512]
    const int* adj  = (const int*)d_in[1];     // [2048][2048]
    const float* W1 = (const float*)d_in[2];   // [8][512][64]
    const float* a1 = (const float*)d_in[3];   // [8][128]
    const float* W2 = (const float*)d_in[4];
    const float* a2 = (const float*)d_in[5];

    float* out  = (float*)d_out;       // h2 [2048][512]
    float* att1 = out + 1048576;       // [8][2048][2048]
    float* att2 = att1 + 33554432;

    char* w = (char*)d_ws;
    unsigned short* Wp1Hi = (unsigned short*)(w);             // 512 KB
    unsigned short* Wp1Lo = (unsigned short*)(w + 524288);    // 512 KB
    unsigned short* Wp2Hi = (unsigned short*)(w + 1048576);   // 512 KB
    unsigned short* Wp2Lo = (unsigned short*)(w + 1572864);   // 512 KB
    unsigned short* Whp   = (unsigned short*)(w + 2097152);   // 2 MB
    float* s1             = (float*)(w + 4194304);            // 64 KB
    float* s2             = (float*)(w + 4259840);            // 64 KB
    unsigned long long* gbits = (unsigned long long*)(w + 4325376);  // 512 KB
    float* x2             = (float*)(w + 4849664);            // 4 MB -> ends ~8.6 MB

    const unsigned int* gbits32 = (const unsigned int*)gbits;

    // merged prep: adjbits (vectorized) + W1/W2 reorder in ONE dispatch
    prep_kernel<<<3072, 256, 0, stream>>>(adj, gbits, W1, Wp1Hi, Wp1Lo,
                                          W2, Wp2Hi, Wp2Lo);

    // ---- layer 1 ----
    gemm1_kernel<<<512, 256, 0, stream>>>(x, Wp1Hi, Wp1Lo, a1, Whp, s1, s2);
    fused_att_kernel<<<1024, 256, 0, stream>>>(s1, s2, gbits32, Whp, att1, x2);

    // ---- layer 2 ----
    gemm1_kernel<<<512, 256, 0, stream>>>(x2, Wp2Hi, Wp2Lo, a2, Whp, s1, s2);
    fused_att_kernel<<<1024, 256, 0, stream>>>(s1, s2, gbits32, Whp, att2, out);
}